// Round 5
// baseline (406.592 us; speedup 1.0000x reference)
//
#include <hip/hip_runtime.h>
#include <math.h>

// Problem constants (fixed by the reference file)
#define T_ 256
#define N_ 64
#define C_ 4096
#define L_ 32
#define SL_ 33            // compact lp slots per (n,t): 0 = blank, 1+l = label l
#define NEGV (-1e30f)

// logaddexp via hardware transcendentals (v_exp_f32/v_log_f32).
// Accuracy ~1e-6 relative; test threshold is 1.27 absolute.
__device__ __forceinline__ float lae2(float a, float b) {
    float m = fmaxf(a, b);
    // if both NEG: exp(0)+exp(0)=2 -> m+ln2, absorbed by |NEG|.
    return m + __logf(__expf(a - m) + __expf(b - m));
}

// whole-wave shift-toward-higher-lane by 1 via DPP (wave_shr:1 = 0x138).
// Lane 0 receives `fill` (bound_ctrl=0 keeps `old` for invalid lanes).
__device__ __forceinline__ float dpp_shr1(float x, float fill) {
    int r = __builtin_amdgcn_update_dpp(__float_as_int(fill), __float_as_int(x),
                                        0x138, 0xF, 0xF, false);
    return __int_as_float(r);
}

__device__ __forceinline__ float wred_max(float v) {
    #pragma unroll
    for (int o = 32; o > 0; o >>= 1) v = fmaxf(v, __shfl_xor(v, o));
    return v;
}
__device__ __forceinline__ float wred_sum(float v) {
    #pragma unroll
    for (int o = 32; o > 0; o >>= 1) v += __shfl_xor(v, o);
    return v;
}

// Kernel 1 (memory-bound, 268 MB): one WAVE per (t,n) row of C=4096.
// 16 float4 per lane held in registers (two-pass max/sum, no re-read),
// wave-level shuffle reductions only: no __syncthreads, no LDS, 16
// outstanding float4 loads per lane (4x the MLP of the block-per-row
// version). ~90 VGPR -> 5 waves/SIMD, plenty for BW saturation.
// Emits only the 33 needed log-probs; block 0 zeroes the scan counter.
__global__ __launch_bounds__(256) void k_row_lse(
        const float* __restrict__ preds, const int* __restrict__ targets,
        float* __restrict__ lp, int* __restrict__ counter) {
    const int wv     = threadIdx.x >> 6;
    const int lane   = threadIdx.x & 63;
    const int row_id = (blockIdx.x << 2) | wv;      // row_id = t*N_ + n
    if (blockIdx.x == 0 && threadIdx.x == 0) *counter = 0;
    const int n = row_id & (N_ - 1);
    const float* row = preds + (size_t)row_id * C_;

    // Gather loads first; independent of the reduction stream.
    float gv = 0.f;
    if (lane < SL_) {
        const int cls = (lane == 0) ? 0 : targets[n * L_ + (lane - 1)];
        gv = row[cls];
    }

    // 4096 floats / 64 lanes = 16x float4 each, coalesced.
    float4 v[16];
    #pragma unroll
    for (int k = 0; k < 16; ++k) v[k] = ((const float4*)row)[lane + (k << 6)];

    float m = v[0].x;
    #pragma unroll
    for (int k = 0; k < 16; ++k)
        m = fmaxf(m, fmaxf(fmaxf(v[k].x, v[k].y), fmaxf(v[k].z, v[k].w)));
    m = wred_max(m);                       // all 64 lanes now hold row max

    float s = 0.f;
    #pragma unroll
    for (int k = 0; k < 16; ++k)
        s += __expf(v[k].x - m) + __expf(v[k].y - m)
           + __expf(v[k].z - m) + __expf(v[k].w - m);
    s = wred_sum(s);
    const float lse = m + __logf(s);

    if (lane < SL_) {
        const int t = row_id >> 6;         // row_id / N_
        lp[((size_t)n * T_ + t) * SL_ + lane] = gv - lse;
    }
}

// Kernel 2 (latency-bound scan): one block per batch item. Waves 1..3 help
// stage lp into LDS then exit; wave 0 runs the T-step alpha recursion with
// lane s owning state s (lane 63 also owns state 64 = blank, which never
// takes the skip transition, so its inputs alpha[63], alpha[64] are local).
// LDS reads are prefetched 4 iterations ahead into a register ring so the
// per-step critical path is pure VALU + hw transcendentals. NOTE: this body
// is the R3-exact arithmetic (absmax 0.0) — R4's reassociated variant
// ((m3+lp_s)+lsum + chunk-hoisted guard) drifted to absmax 1.25/1.27. Do
// not re-order the comb/na adds. Last block reduces partials to the mean.
__global__ __launch_bounds__(256) void k_ctc_scan(
        const float* __restrict__ lp, const int* __restrict__ targets,
        const int* __restrict__ plen, const int* __restrict__ tlen,
        float* __restrict__ partial, int* __restrict__ counter,
        float* __restrict__ out) {
    // Pad: deepest prefetch index is (253+4+3)*SL_+32; (T_+16)*SL_ covers it.
    __shared__ __align__(16) float lds[(T_ + 16) * SL_];   // 35.9 KB
    const int n = blockIdx.x;
    const int tid = threadIdx.x;
    const float4* src = (const float4*)(lp + (size_t)n * T_ * SL_);
    float4* dst = (float4*)lds;
    for (int i = tid; i < (T_ * SL_) / 4; i += 256) dst[i] = src[i];
    __syncthreads();
    if (tid >= 64) return;                 // no further barriers

    const int lane = tid;
    const int tl = tlen[n];
    const int pl = plen[n];
    const int ends = 2 * tl;
    const bool odd = (lane & 1);
    const int slot   = odd ? 1 + (lane >> 1) : 0;
    const int cls    = odd ? targets[n * L_ + (lane >> 1)] : 0;
    const int clsm2  = (odd && lane >= 2) ? targets[n * L_ + (lane >> 1) - 1] : 0;
    const bool skip  = odd && (lane >= 2) && (cls != 0) && (cls != clsm2);
    const bool valid   = lane < 2 * tl + 1;
    const bool valid64 = (2 * tl + 1) > 64;    // is state 64 valid

    // alpha0: only s=0 (blank) and s=1 (first label, if tl>0) are live.
    float a = NEGV, b = NEGV;                  // a = alpha[lane], b = alpha[64] (lane 63)
    if (lane == 0) a = lds[0];
    if (lane == 1 && tl > 0) a = lds[1];

    // Depth-4 register ring: pf[j] holds step t+j's lp while chunk t runs.
    float pf_s[4], pf_b[4];
    #pragma unroll
    for (int j = 0; j < 4; ++j) {
        pf_s[j] = lds[(1 + j) * SL_ + slot];
        pf_b[j] = lds[(1 + j) * SL_];
    }
    // Steps 1..256 in 64 chunks of 4. Step 256 is a dummy (tt < pl is false
    // with pl<=T_, so its result — computed from padded/garbage lp — is
    // discarded by the cndmask). Prefetch indices stay inside the padded lds.
    for (int t = 1; t <= T_; t += 4) {
        #pragma unroll
        for (int j = 0; j < 4; ++j) {
            const float lp_s = pf_s[j];
            const float lp64 = pf_b[j];
            pf_s[j] = lds[(t + 4 + j) * SL_ + slot];   // prefetch step t+4+j
            pf_b[j] = lds[(t + 4 + j) * SL_];

            const float a2 = dpp_shr1(a, NEGV);        // alpha[lane-1]
            float a3 = dpp_shr1(a2, NEGV);             // alpha[lane-2]
            a3 = skip ? a3 : NEGV;
            // 3-way logsumexp, one log on the chain:
            const float m3 = fmaxf(fmaxf(a, a2), a3);
            const float comb = m3 + __logf(__expf(a - m3) + __expf(a2 - m3)
                                           + __expf(a3 - m3));
            // state 64 (only lane 63's value is meaningful):
            const float nb = valid64 ? (lae2(b, a) + lp64) : NEGV;
            const float na = valid ? (comb + lp_s) : NEGV;
            const int tt = t + j;
            if (tt < pl) { a = na; b = nb; }           // wave-uniform predicate
        }
    }

    const float a_last = (ends >= 64) ? __shfl(b, 63) : __shfl(a, ends);
    float a_prev = __shfl(a, (ends > 0) ? (ends - 1) : 0);
    if (tl <= 0) a_prev = NEGV;
    float nll = -lae2(a_last, a_prev);
    if (!(isfinite(nll) && nll < 1e29f)) nll = 0.f;
    if (lane == 0) partial[n] = nll / (float)((tl > 0) ? tl : 1);

    // Last-block-done mean reduction (release: store+fence+atomic; acquire:
    // fence after observing the final count). atomicAdd is device-scope.
    __threadfence();
    int done = 0;
    if (lane == 0) done = atomicAdd(counter, 1);
    done = __shfl(done, 0);
    if (done == N_ - 1) {
        __threadfence();
        float v = partial[lane];               // lane n reads partial[n]
        v = wred_sum(v);
        if (lane == 0) out[0] = v * (1.0f / (float)N_);
    }
}

extern "C" void kernel_launch(void* const* d_in, const int* in_sizes, int n_in,
                              void* d_out, int out_size, void* d_ws, size_t ws_size,
                              hipStream_t stream) {
    const float* preds   = (const float*)d_in[0];
    const int*   targets = (const int*)d_in[1];
    const int*   plen    = (const int*)d_in[2];
    const int*   tlen    = (const int*)d_in[3];

    float* lp      = (float*)d_ws;                    // N*T*33 floats = 2.16 MB
    float* partial = lp + (size_t)N_ * T_ * SL_;      // +64 floats
    int*   counter = (int*)(partial + N_);            // +1 int

    k_row_lse<<<(T_ * N_) / 4, 256, 0, stream>>>(preds, targets, lp, counter);
    k_ctc_scan<<<N_, 256, 0, stream>>>(lp, targets, plen, tlen, partial,
                                       counter, (float*)d_out);
}

// Round 7
// 393.251 us; speedup vs baseline: 1.0339x; 1.0339x over previous
//
#include <hip/hip_runtime.h>
#include <math.h>

// Problem constants (fixed by the reference file)
#define T_ 256
#define N_ 64
#define C_ 4096
#define L_ 32
#define SL_ 33            // compact slots per (n,t): 0 = blank, 1+l = label l
#define NEGV (-1e30f)

// whole-wave shift-toward-higher-lane by 1 via DPP (wave_shr:1 = 0x138).
// Lane 0 receives `fill`.
__device__ __forceinline__ float dpp_shr1(float x, float fill) {
    int r = __builtin_amdgcn_update_dpp(__float_as_int(fill), __float_as_int(x),
                                        0x138, 0xF, 0xF, false);
    return __int_as_float(r);
}

__device__ __forceinline__ float wred_max(float v) {
    #pragma unroll
    for (int o = 32; o > 0; o >>= 1) v = fmaxf(v, __shfl_xor(v, o));
    return v;
}
__device__ __forceinline__ float wred_sum(float v) {
    #pragma unroll
    for (int o = 32; o > 0; o >>= 1) v += __shfl_xor(v, o);
    return v;
}

// Kernel 1 (memory-bound, 268 MB): one WAVE per (t,n) row of C=4096.
// R5-exact reduction; the only change is the store: p = exp(lp) (softmax
// probability) instead of lp, feeding the linear-domain scan. Block 0
// zeroes the scan completion counter.
__global__ __launch_bounds__(256) void k_row_lse(
        const float* __restrict__ preds, const int* __restrict__ targets,
        float* __restrict__ pmat, int* __restrict__ counter) {
    const int wv     = threadIdx.x >> 6;
    const int lane   = threadIdx.x & 63;
    const int row_id = (blockIdx.x << 2) | wv;      // row_id = t*N_ + n
    if (blockIdx.x == 0 && threadIdx.x == 0) *counter = 0;
    const int n = row_id & (N_ - 1);
    const float* row = preds + (size_t)row_id * C_;

    // Gather loads first; independent of the reduction stream.
    float gv = 0.f;
    if (lane < SL_) {
        const int cls = (lane == 0) ? 0 : targets[n * L_ + (lane - 1)];
        gv = row[cls];
    }

    // 4096 floats / 64 lanes = 16x float4 each, coalesced.
    float4 v[16];
    #pragma unroll
    for (int k = 0; k < 16; ++k) v[k] = ((const float4*)row)[lane + (k << 6)];

    float m = v[0].x;
    #pragma unroll
    for (int k = 0; k < 16; ++k)
        m = fmaxf(m, fmaxf(fmaxf(v[k].x, v[k].y), fmaxf(v[k].z, v[k].w)));
    m = wred_max(m);                       // all 64 lanes now hold row max

    float s = 0.f;
    #pragma unroll
    for (int k = 0; k < 16; ++k)
        s += __expf(v[k].x - m) + __expf(v[k].y - m)
           + __expf(v[k].z - m) + __expf(v[k].w - m);
    s = wred_sum(s);
    const float lse = m + __logf(s);

    if (lane < SL_) {
        const int t = row_id >> 6;         // row_id / N_
        pmat[((size_t)n * T_ + t) * SL_ + lane] = __expf(gv - lse);
    }
}

// Kernel 2: linear-domain (Rabiner-scaled) CTC forward. One block per batch
// item; waves 1..3 help stage p into LDS then exit; wave 0 runs T steps with
// lane s owning state s (lane 63 also owns state 64 = blank; its inputs
// B, A[63] are lane-local). Per-step chain is 2 DPP + 2 add + 1 mul + masks
// (~32 cyc) — NO transcendentals (R2-R5's log-domain step had 7 trans ops
// and was stuck at ~470 cyc/step). Every 4 steps: wave-max rescale, with
// log(scale) accumulated into Slog off the critical path. Underflow math:
// p >= e^-16 per step -> worst decay e^-64 per 4-step chunk, far above
// denormal range after each rescale-to-1. Growth bound: A<=1, sum3<=3A -> 81
// max per chunk, no overflow. Last block reduces partials to the mean.
__global__ __launch_bounds__(256) void k_ctc_scan(
        const float* __restrict__ pmat, const int* __restrict__ targets,
        const int* __restrict__ plen, const int* __restrict__ tlen,
        float* __restrict__ partial, int* __restrict__ counter,
        float* __restrict__ out) {
    // Pad: deepest prefetch index is (253+4+3)*SL_+32; (T_+16)*SL_ covers it.
    __shared__ __align__(16) float lds[(T_ + 16) * SL_];   // 35.9 KB
    const int n = blockIdx.x;
    const int tid = threadIdx.x;
    const float4* src = (const float4*)(pmat + (size_t)n * T_ * SL_);
    float4* dst = (float4*)lds;
    for (int i = tid; i < (T_ * SL_) / 4; i += 256) dst[i] = src[i];
    __syncthreads();
    if (tid >= 64) return;                 // no further barriers

    const int lane = tid;
    const int tl = tlen[n];
    const int pl = plen[n];
    const int ends = 2 * tl;
    const bool odd = (lane & 1);
    const int slot   = odd ? 1 + (lane >> 1) : 0;
    const int cls    = odd ? targets[n * L_ + (lane >> 1)] : 0;
    const int clsm2  = (odd && lane >= 2) ? targets[n * L_ + (lane >> 1) - 1] : 0;
    const bool skip  = odd && (lane >= 2) && (cls != 0) && (cls != clsm2);
    const bool valid   = lane < 2 * tl + 1;
    const bool valid64 = (2 * tl + 1) > 64;    // is state 64 valid

    // alpha0 (linear): only s=0 and s=1 (if tl>0) live; dead states = 0.
    float A = 0.f, B = 0.f;     // A = alpha[lane], B = alpha[64] (lane 63)
    float Slog = 0.f;           // accumulated log of rescale factors
    if (lane == 0) A = lds[0];
    if (lane == 1 && tl > 0) A = lds[1];

    // Depth-4 register ring: pf[j] holds step t+j's p while chunk t runs.
    float pf_s[4], pf_b[4];
    #pragma unroll
    for (int j = 0; j < 4; ++j) {
        pf_s[j] = lds[(1 + j) * SL_ + slot];
        pf_b[j] = lds[(1 + j) * SL_];
    }

    // Steps 1..256 in 64 chunks of 4. Step 256 is a dummy (t+j < pl is false
    // with pl<=T_, so its result — from padded/garbage LDS, possibly NaN —
    // is discarded by the cndmask; cndmask is NaN-safe, never multiply
    // garbage by 0). Prefetch indices stay inside the padded lds.
    for (int t = 1; t <= T_; t += 4) {
        #pragma unroll
        for (int j = 0; j < 4; ++j) {
            const float p_s = pf_s[j];
            const float p_b = pf_b[j];
            pf_s[j] = lds[(t + 4 + j) * SL_ + slot];   // prefetch step t+4+j
            pf_b[j] = lds[(t + 4 + j) * SL_];

            const float A2 = dpp_shr1(A, 0.f);         // alpha[lane-1]
            float A3 = dpp_shr1(A2, 0.f);              // alpha[lane-2]
            A3 = skip ? A3 : 0.f;
            const float sum3 = (A + A2) + A3;
            const float nA = valid ? sum3 * p_s : 0.f;
            const float nB = valid64 ? (B + A) * p_b : 0.f;
            if (t + j < pl) { A = nA; B = nB; }        // wave-uniform predicate
        }
        // Rescale only when the whole chunk updated (t+3 < pl); a straddling
        // chunk skips it (<= 4 unrescaled steps, decay >= e^-64: safe), and
        // frozen chunks must not rescale (would corrupt the held alpha).
        if (t + 3 < pl) {
            float mx = fmaxf(A, (lane == 63) ? B : 0.f);
            mx = wred_max(mx);
            if (mx > 0.f) {
                const float inv = 1.0f / mx;
                A *= inv; B *= inv;
                Slog += __logf(mx);        // off the per-step chain
            }
        }
    }

    const float a_last = (ends >= 64) ? __shfl(B, 63) : __shfl(A, ends);
    float a_prev = __shfl(A, (ends > 0) ? (ends - 1) : 0);
    if (tl <= 0) a_prev = 0.f;
    // All-paths-dead: sum==0 -> logf -> -inf -> nll=+inf -> filtered to 0,
    // matching the reference's (isfinite && <1e29) semantics.
    float nll = -(__logf(a_last + a_prev) + Slog);
    if (!(isfinite(nll) && nll < 1e29f)) nll = 0.f;
    if (lane == 0) partial[n] = nll / (float)((tl > 0) ? tl : 1);

    // Last-block-done mean reduction (proven pattern from R2-R5).
    __threadfence();
    int done = 0;
    if (lane == 0) done = atomicAdd(counter, 1);
    done = __shfl(done, 0);
    if (done == N_ - 1) {
        __threadfence();
        float v = partial[lane];               // lane n reads partial[n]
        v = wred_sum(v);
        if (lane == 0) out[0] = v * (1.0f / (float)N_);
    }
}

extern "C" void kernel_launch(void* const* d_in, const int* in_sizes, int n_in,
                              void* d_out, int out_size, void* d_ws, size_t ws_size,
                              hipStream_t stream) {
    const float* preds   = (const float*)d_in[0];
    const int*   targets = (const int*)d_in[1];
    const int*   plen    = (const int*)d_in[2];
    const int*   tlen    = (const int*)d_in[3];

    float* pmat    = (float*)d_ws;                    // N*T*33 floats = 2.16 MB
    float* partial = pmat + (size_t)N_ * T_ * SL_;    // +64 floats
    int*   counter = (int*)(partial + N_);            // +1 int

    k_row_lse<<<(T_ * N_) / 4, 256, 0, stream>>>(preds, targets, pmat, counter);
    k_ctc_scan<<<N_, 256, 0, stream>>>(pmat, targets, plen, tlen, partial,
                                       counter, (float*)d_out);
}